// Round 3
// baseline (979.698 us; speedup 1.0000x reference)
//
#include <hip/hip_runtime.h>

#define N_NODES 50000
#define N_EDGES 640000
#define HID 128
#define EDGE_DIM 32
#define NUM_GRAPHS 512
#define BN_EPS 1e-5f

// ---------------------------------------------------------------------------
// deg[d] = number of edges with dst == d
// ---------------------------------------------------------------------------
__global__ void deg_hist_kernel(const int* __restrict__ eidx, int* __restrict__ deg) {
    int e = blockIdx.x * 256 + threadIdx.x;
    if (e >= N_EDGES) return;
    atomicAdd(&deg[eidx[N_EDGES + e]], 1);
}

// Single-block exclusive scan of deg -> rowp (N_NODES+1 entries)
__global__ void scan_kernel(const int* __restrict__ deg, int* __restrict__ rowp) {
    __shared__ int ssum[1024];
    int t = threadIdx.x;
    const int n = N_NODES;
    int strip = (n + 1023) >> 10;
    int s0 = t * strip, s1 = min(s0 + strip, n);
    int local = 0;
    for (int i = s0; i < s1; ++i) local += deg[i];
    ssum[t] = local;
    __syncthreads();
    for (int off = 1; off < 1024; off <<= 1) {
        int v = (t >= off) ? ssum[t - off] : 0;
        __syncthreads();
        ssum[t] += v;
        __syncthreads();
    }
    int excl = (t == 0) ? 0 : ssum[t - 1];
    for (int i = s0; i < s1; ++i) { rowp[i] = excl; excl += deg[i]; }
    if (t == 1023) rowp[n] = ssum[1023];
}

// CSR fill: csr_src[p] = source node, csr_eid[p] = edge id
__global__ void fill_csr_kernel(const int* __restrict__ eidx,
                                const int* __restrict__ rowp,
                                int* __restrict__ cursor,
                                int* __restrict__ csr_src,
                                int* __restrict__ csr_eid) {
    int e = blockIdx.x * 256 + threadIdx.x;
    if (e >= N_EDGES) return;
    int d = eidx[N_EDGES + e];
    int pos = rowp[d] + atomicAdd(&cursor[d], 1);
    csr_src[pos] = eidx[e];
    csr_eid[pos] = e;
}

// Ea[d] = sum of edge_attr rows with dst == d (CSR gather, no float atomics)
__global__ void ea_gather_kernel(const float* __restrict__ edge_attr,
                                 const int* __restrict__ rowp,
                                 const int* __restrict__ csr_eid,
                                 float* __restrict__ Ea) {
    int node = blockIdx.x * 8 + (threadIdx.x >> 5);
    int c = threadIdx.x & 31;
    if (node >= N_NODES) return;
    int beg = rowp[node], end = rowp[node + 1];
    float s = 0.f;
    for (int p = beg; p < end; ++p)
        s += edge_attr[csr_eid[p] * EDGE_DIM + c];
    Ea[node * EDGE_DIM + c] = s;
}

// ---------------------------------------------------------------------------
// Fused per-layer GEMM (optionally applying BN+ReLU of the PREVIOUS layer to
// the X tile as it is loaded):
//   xin    = BN ? relu(X*scale + shift) : X
//   h[i]   = xin[i] @ Wn + bn                     (K = 128)
//   acc[i] = h[i] + Ea[i] @ We + deg[i] * be      (K = 32)
// block = 256 threads, 32 rows/block; thread owns 4 rows x 4 cols
// ---------------------------------------------------------------------------
template <bool BN>
__global__ __launch_bounds__(256) void gemm_base_kernel(
        const float* __restrict__ X, const float* __restrict__ Wn,
        const float* __restrict__ bnb,
        const float* __restrict__ Ea, const float* __restrict__ We,
        const float* __restrict__ be, const int* __restrict__ rowp,
        const float* __restrict__ scale, const float* __restrict__ shift,
        float* __restrict__ h, float* __restrict__ acc) {
    __shared__ float Xs[32][32];
    __shared__ float Ws[32][128];
    int tid = threadIdx.x;
    int r0b = blockIdx.x * 32;
    int c4 = (tid & 31) * 4;
    int rt = (tid >> 5) * 4;
    float4 accv[4];
    #pragma unroll
    for (int r = 0; r < 4; ++r) accv[r] = make_float4(0.f, 0.f, 0.f, 0.f);

    int lrow = tid >> 3;               // 0..31
    int lk4  = (tid & 7) * 4;          // 0,4,...,28
    int grow = min(r0b + lrow, N_NODES - 1);

    // ---- phase 1: X @ Wn, K = 128 ----
    for (int kb = 0; kb < 128; kb += 32) {
        __syncthreads();
        float4 xv4 = *(const float4*)&X[grow * 128 + kb + lk4];
        if (BN) {
            float4 sc4 = *(const float4*)&scale[kb + lk4];
            float4 sh4 = *(const float4*)&shift[kb + lk4];
            xv4.x = fmaxf(0.f, xv4.x * sc4.x + sh4.x);
            xv4.y = fmaxf(0.f, xv4.y * sc4.y + sh4.y);
            xv4.z = fmaxf(0.f, xv4.z * sc4.z + sh4.z);
            xv4.w = fmaxf(0.f, xv4.w * sc4.w + sh4.w);
        }
        *(float4*)&Xs[lrow][lk4] = xv4;
        #pragma unroll
        for (int j = 0; j < 4; ++j) {
            int fi = tid + j * 256;
            int kk = fi >> 5, cc = (fi & 31) * 4;
            *(float4*)&Ws[kk][cc] = *(const float4*)&Wn[(kb + kk) * 128 + cc];
        }
        __syncthreads();
        #pragma unroll
        for (int k = 0; k < 32; ++k) {
            float4 w = *(float4*)&Ws[k][c4];
            #pragma unroll
            for (int r = 0; r < 4; ++r) {
                float xv = Xs[rt + r][k];
                accv[r].x += xv * w.x; accv[r].y += xv * w.y;
                accv[r].z += xv * w.z; accv[r].w += xv * w.w;
            }
        }
    }
    // h = partial + bn ; write h
    float4 bn4 = *(const float4*)&bnb[c4];
    #pragma unroll
    for (int r = 0; r < 4; ++r) {
        accv[r].x += bn4.x; accv[r].y += bn4.y;
        accv[r].z += bn4.z; accv[r].w += bn4.w;
        int row = r0b + rt + r;
        if (row < N_NODES) *(float4*)&h[row * 128 + c4] = accv[r];
    }
    // ---- phase 2: Ea @ We, K = 32 ----
    __syncthreads();
    *(float4*)&Xs[lrow][lk4] = *(const float4*)&Ea[grow * EDGE_DIM + lk4];
    #pragma unroll
    for (int j = 0; j < 4; ++j) {
        int fi = tid + j * 256;
        int kk = fi >> 5, cc = (fi & 31) * 4;
        *(float4*)&Ws[kk][cc] = *(const float4*)&We[kk * 128 + cc];
    }
    __syncthreads();
    #pragma unroll
    for (int k = 0; k < 32; ++k) {
        float4 w = *(float4*)&Ws[k][c4];
        #pragma unroll
        for (int r = 0; r < 4; ++r) {
            float xv = Xs[rt + r][k];
            accv[r].x += xv * w.x; accv[r].y += xv * w.y;
            accv[r].z += xv * w.z; accv[r].w += xv * w.w;
        }
    }
    float4 be4 = *(const float4*)&be[c4];
    #pragma unroll
    for (int r = 0; r < 4; ++r) {
        int row = r0b + rt + r;
        if (row < N_NODES) {
            float dg = (float)(rowp[row + 1] - rowp[row]);
            accv[r].x += dg * be4.x; accv[r].y += dg * be4.y;
            accv[r].z += dg * be4.z; accv[r].w += dg * be4.w;
            *(float4*)&acc[row * 128 + c4] = accv[r];
        }
    }
}

// ---------------------------------------------------------------------------
// acc[d] += sum over CSR edges of h[src]; fused column stats (sum / sumsq)
// 128 threads (thread = column), NPB nodes per block, 2 atomics/thread/block
// ---------------------------------------------------------------------------
#define NPB 8
__global__ __launch_bounds__(128) void gather_stats_kernel(
        const float* __restrict__ h,
        const int* __restrict__ rowp, const int* __restrict__ csr_src,
        float* __restrict__ acc, float* __restrict__ cs, float* __restrict__ cq) {
    int c = threadIdx.x;
    int n0 = blockIdx.x * NPB;
    float s_sum = 0.f, q_sum = 0.f;
    #pragma unroll
    for (int i = 0; i < NPB; ++i) {
        int node = n0 + i;
        if (node >= N_NODES) break;
        int beg = rowp[node], end = rowp[node + 1];
        float s = acc[node * 128 + c];
        int p = beg;
        for (; p + 1 < end; p += 2) {
            s += h[csr_src[p] * 128 + c] + h[csr_src[p + 1] * 128 + c];
        }
        if (p < end) s += h[csr_src[p] * 128 + c];
        acc[node * 128 + c] = s;
        s_sum += s; q_sum += s * s;
    }
    unsafeAtomicAdd(&cs[c], s_sum);
    unsafeAtomicAdd(&cq[c], q_sum);
}

// scale/shift from column stats: y = x*scale[c] + shift[c]
__global__ void prep_bn_kernel(const float* __restrict__ cs, const float* __restrict__ cq,
                               const float* __restrict__ gamma, const float* __restrict__ beta,
                               float* __restrict__ scale, float* __restrict__ shift) {
    int c = threadIdx.x;
    const float invN = 1.0f / (float)N_NODES;
    float m = cs[c] * invN;
    float var = cq[c] * invN - m * m;
    float sc = gamma[c] * rsqrtf(var + BN_EPS);
    scale[c] = sc;
    shift[c] = beta[c] - m * sc;
}

// ---------------------------------------------------------------------------
// One block per graph (batch is sorted): binary-search node range, apply
// layer-3 BN+ReLU inline, mean-pool, then the 128->2 FC. No atomics.
// ---------------------------------------------------------------------------
__global__ __launch_bounds__(256) void pool_fc_kernel(
        const float* __restrict__ acc,
        const float* __restrict__ scale, const float* __restrict__ shift,
        const int* __restrict__ batch,
        const float* __restrict__ Wfc, const float* __restrict__ bfc,
        float* __restrict__ out) {
    __shared__ float ps[256];
    int g = blockIdx.x;
    int lo = 0, hi = N_NODES;
    while (lo < hi) { int mid = (lo + hi) >> 1; if (batch[mid] < g) lo = mid + 1; else hi = mid; }
    int start = lo;
    hi = N_NODES;
    while (lo < hi) { int mid = (lo + hi) >> 1; if (batch[mid] < g + 1) lo = mid + 1; else hi = mid; }
    int end = lo;

    int c = threadIdx.x & 127;
    int half = threadIdx.x >> 7;
    float sc = scale[c], sh = shift[c];
    float s = 0.f;
    for (int r = start + half; r < end; r += 2)
        s += fmaxf(0.f, acc[r * 128 + c] * sc + sh);
    ps[threadIdx.x] = s;
    __syncthreads();
    if (half == 0)
        ps[c] = (ps[c] + ps[c + 128]) / fmaxf((float)(end - start), 1.0f);
    __syncthreads();
    if (threadIdx.x < 2) {
        int o = threadIdx.x;
        float t = 0.f;
        #pragma unroll 16
        for (int cc = 0; cc < 128; ++cc) t += ps[cc] * Wfc[cc * 2 + o];
        out[g * 2 + o] = t + bfc[o];
    }
}

// ---------------------------------------------------------------------------
extern "C" void kernel_launch(void* const* d_in, const int* in_sizes, int n_in,
                              void* d_out, int out_size, void* d_ws, size_t ws_size,
                              hipStream_t stream) {
    const float* x         = (const float*)d_in[0];
    const float* edge_attr = (const float*)d_in[1];
    const int*   eidx      = (const int*)d_in[2];
    const int*   batch     = (const int*)d_in[3];
    const float* Wn[3]  = {(const float*)d_in[4],  (const float*)d_in[8],  (const float*)d_in[12]};
    const float* bnb[3] = {(const float*)d_in[5],  (const float*)d_in[9],  (const float*)d_in[13]};
    const float* We[3]  = {(const float*)d_in[6],  (const float*)d_in[10], (const float*)d_in[14]};
    const float* be[3]  = {(const float*)d_in[7],  (const float*)d_in[11], (const float*)d_in[15]};
    const float* gm[3]  = {(const float*)d_in[16], (const float*)d_in[18], (const float*)d_in[20]};
    const float* bt[3]  = {(const float*)d_in[17], (const float*)d_in[19], (const float*)d_in[21]};
    const float* Wfc = (const float*)d_in[22];
    const float* bfc = (const float*)d_in[23];
    float* out = (float*)d_out;

    char* p = (char*)d_ws;
    auto alloc = [&](size_t bytes) {
        char* q = p;
        p += (bytes + 255) & ~size_t(255);
        return q;
    };
    float* Ea     = (float*)alloc(sizeof(float) * N_NODES * EDGE_DIM);
    float* hbuf   = (float*)alloc(sizeof(float) * N_NODES * HID);
    float* accA   = (float*)alloc(sizeof(float) * N_NODES * HID);
    float* accB   = (float*)alloc(sizeof(float) * N_NODES * HID);
    float* cs     = (float*)alloc(sizeof(float) * HID);      // cs and cq contiguous
    float* cq     = (float*)alloc(sizeof(float) * HID);
    float* scale  = (float*)alloc(sizeof(float) * HID);
    float* shift  = (float*)alloc(sizeof(float) * HID);
    int*   deg    = (int*)alloc(sizeof(int) * N_NODES);
    int*   rowp   = (int*)alloc(sizeof(int) * (N_NODES + 1));
    int*   cursor = (int*)alloc(sizeof(int) * N_NODES);
    int*   csr    = (int*)alloc(sizeof(int) * N_EDGES);
    int*   csre   = (int*)alloc(sizeof(int) * N_EDGES);

    // zero all accumulation buffers every call (harness does not re-poison)
    hipMemsetAsync(deg, 0, sizeof(int) * N_NODES, stream);
    hipMemsetAsync(cursor, 0, sizeof(int) * N_NODES, stream);

    deg_hist_kernel<<<(N_EDGES + 255) / 256, 256, 0, stream>>>(eidx, deg);
    scan_kernel<<<1, 1024, 0, stream>>>(deg, rowp);
    fill_csr_kernel<<<(N_EDGES + 255) / 256, 256, 0, stream>>>(eidx, rowp, cursor, csr, csre);
    ea_gather_kernel<<<(N_NODES + 7) / 8, 256, 0, stream>>>(edge_attr, rowp, csre, Ea);

    float* accs[3] = {accA, accB, accA};
    const int ngrid = (N_NODES + 31) / 32;
    const float* X = x;
    for (int l = 0; l < 3; ++l) {
        hipMemsetAsync(cs, 0, sizeof(float) * HID * 2, stream);  // cs + cq
        float* acc = accs[l];
        if (l == 0) {
            gemm_base_kernel<false><<<ngrid, 256, 0, stream>>>(
                X, Wn[l], bnb[l], Ea, We[l], be[l], rowp, nullptr, nullptr, hbuf, acc);
        } else {
            gemm_base_kernel<true><<<ngrid, 256, 0, stream>>>(
                X, Wn[l], bnb[l], Ea, We[l], be[l], rowp, scale, shift, hbuf, acc);
        }
        gather_stats_kernel<<<(N_NODES + NPB - 1) / NPB, 128, 0, stream>>>(
            hbuf, rowp, csr, acc, cs, cq);
        prep_bn_kernel<<<1, 128, 0, stream>>>(cs, cq, gm[l], bt[l], scale, shift);
        X = acc;
    }
    pool_fc_kernel<<<NUM_GRAPHS, 256, 0, stream>>>(
        accs[2], scale, shift, batch, Wfc, bfc, out);
}

// Round 4
// 638.824 us; speedup vs baseline: 1.5336x; 1.5336x over previous
//
#include <hip/hip_runtime.h>

#define N_NODES 50000
#define N_EDGES 640000
#define HID 128
#define EDGE_DIM 32
#define NUM_GRAPHS 512
#define BN_EPS 1e-5f

typedef unsigned int uint32;
typedef unsigned short ushort16;

// round-to-nearest-even f32 -> bf16 bits
__device__ inline ushort16 f2bf(float x) {
    uint32 u = __float_as_uint(x);
    return (ushort16)((u + 0x7fff + ((u >> 16) & 1)) >> 16);
}

// ---------------------------------------------------------------------------
// deg[d] = number of edges with dst == d
// ---------------------------------------------------------------------------
__global__ void deg_hist_kernel(const int* __restrict__ eidx, int* __restrict__ deg) {
    int e = blockIdx.x * 256 + threadIdx.x;
    if (e >= N_EDGES) return;
    atomicAdd(&deg[eidx[N_EDGES + e]], 1);
}

// Single-block exclusive scan of deg -> rowp (N_NODES+1 entries)
__global__ void scan_kernel(const int* __restrict__ deg, int* __restrict__ rowp) {
    __shared__ int ssum[1024];
    int t = threadIdx.x;
    const int n = N_NODES;
    int strip = (n + 1023) >> 10;
    int s0 = t * strip, s1 = min(s0 + strip, n);
    int local = 0;
    for (int i = s0; i < s1; ++i) local += deg[i];
    ssum[t] = local;
    __syncthreads();
    for (int off = 1; off < 1024; off <<= 1) {
        int v = (t >= off) ? ssum[t - off] : 0;
        __syncthreads();
        ssum[t] += v;
        __syncthreads();
    }
    int excl = (t == 0) ? 0 : ssum[t - 1];
    for (int i = s0; i < s1; ++i) { rowp[i] = excl; excl += deg[i]; }
    if (t == 1023) rowp[n] = ssum[1023];
}

// CSR fill: csr_src[p] = source node, csr_eid[p] = edge id
__global__ void fill_csr_kernel(const int* __restrict__ eidx,
                                const int* __restrict__ rowp,
                                int* __restrict__ cursor,
                                int* __restrict__ csr_src,
                                int* __restrict__ csr_eid) {
    int e = blockIdx.x * 256 + threadIdx.x;
    if (e >= N_EDGES) return;
    int d = eidx[N_EDGES + e];
    int pos = rowp[d] + atomicAdd(&cursor[d], 1);
    csr_src[pos] = eidx[e];
    csr_eid[pos] = e;
}

// Ea[d] = sum of edge_attr rows with dst == d (CSR gather, no float atomics)
__global__ void ea_gather_kernel(const float* __restrict__ edge_attr,
                                 const int* __restrict__ rowp,
                                 const int* __restrict__ csr_eid,
                                 float* __restrict__ Ea) {
    int node = blockIdx.x * 8 + (threadIdx.x >> 5);
    int c = threadIdx.x & 31;
    if (node >= N_NODES) return;
    int beg = rowp[node], end = rowp[node + 1];
    float s = 0.f;
    for (int p = beg; p < end; ++p)
        s += edge_attr[csr_eid[p] * EDGE_DIM + c];
    Ea[node * EDGE_DIM + c] = s;
}

// ---------------------------------------------------------------------------
// Fused per-layer GEMM (optionally applying BN+ReLU of the PREVIOUS layer to
// the X tile as it is loaded):
//   xin    = BN ? relu(X*scale + shift) : X
//   h[i]   = xin[i] @ Wn + bn      -> written as bf16 (gather operand only)
//   acc[i] = h[i](fp32) + Ea[i] @ We + deg[i] * be
// block = 256 threads, 32 rows/block; thread owns 4 rows x 4 cols
// ---------------------------------------------------------------------------
template <bool BN>
__global__ __launch_bounds__(256) void gemm_base_kernel(
        const float* __restrict__ X, const float* __restrict__ Wn,
        const float* __restrict__ bnb,
        const float* __restrict__ Ea, const float* __restrict__ We,
        const float* __restrict__ be, const int* __restrict__ rowp,
        const float* __restrict__ scale, const float* __restrict__ shift,
        ushort16* __restrict__ hb, float* __restrict__ acc) {
    __shared__ float Xs[32][32];
    __shared__ float Ws[32][128];
    int tid = threadIdx.x;
    int r0b = blockIdx.x * 32;
    int c4 = (tid & 31) * 4;
    int rt = (tid >> 5) * 4;
    float4 accv[4];
    #pragma unroll
    for (int r = 0; r < 4; ++r) accv[r] = make_float4(0.f, 0.f, 0.f, 0.f);

    int lrow = tid >> 3;               // 0..31
    int lk4  = (tid & 7) * 4;          // 0,4,...,28
    int grow = min(r0b + lrow, N_NODES - 1);

    // ---- phase 1: X @ Wn, K = 128 ----
    for (int kb = 0; kb < 128; kb += 32) {
        __syncthreads();
        float4 xv4 = *(const float4*)&X[grow * 128 + kb + lk4];
        if (BN) {
            float4 sc4 = *(const float4*)&scale[kb + lk4];
            float4 sh4 = *(const float4*)&shift[kb + lk4];
            xv4.x = fmaxf(0.f, xv4.x * sc4.x + sh4.x);
            xv4.y = fmaxf(0.f, xv4.y * sc4.y + sh4.y);
            xv4.z = fmaxf(0.f, xv4.z * sc4.z + sh4.z);
            xv4.w = fmaxf(0.f, xv4.w * sc4.w + sh4.w);
        }
        *(float4*)&Xs[lrow][lk4] = xv4;
        #pragma unroll
        for (int j = 0; j < 4; ++j) {
            int fi = tid + j * 256;
            int kk = fi >> 5, cc = (fi & 31) * 4;
            *(float4*)&Ws[kk][cc] = *(const float4*)&Wn[(kb + kk) * 128 + cc];
        }
        __syncthreads();
        #pragma unroll
        for (int k = 0; k < 32; ++k) {
            float4 w = *(float4*)&Ws[k][c4];
            #pragma unroll
            for (int r = 0; r < 4; ++r) {
                float xv = Xs[rt + r][k];
                accv[r].x += xv * w.x; accv[r].y += xv * w.y;
                accv[r].z += xv * w.z; accv[r].w += xv * w.w;
            }
        }
    }
    // h = partial + bn ; write h as packed bf16
    float4 bn4 = *(const float4*)&bnb[c4];
    #pragma unroll
    for (int r = 0; r < 4; ++r) {
        accv[r].x += bn4.x; accv[r].y += bn4.y;
        accv[r].z += bn4.z; accv[r].w += bn4.w;
        int row = r0b + rt + r;
        if (row < N_NODES) {
            uint2 pk;
            pk.x = (uint32)f2bf(accv[r].x) | ((uint32)f2bf(accv[r].y) << 16);
            pk.y = (uint32)f2bf(accv[r].z) | ((uint32)f2bf(accv[r].w) << 16);
            *(uint2*)&hb[row * 128 + c4] = pk;
        }
    }
    // ---- phase 2: Ea @ We, K = 32 ----
    __syncthreads();
    *(float4*)&Xs[lrow][lk4] = *(const float4*)&Ea[grow * EDGE_DIM + lk4];
    #pragma unroll
    for (int j = 0; j < 4; ++j) {
        int fi = tid + j * 256;
        int kk = fi >> 5, cc = (fi & 31) * 4;
        *(float4*)&Ws[kk][cc] = *(const float4*)&We[kk * 128 + cc];
    }
    __syncthreads();
    #pragma unroll
    for (int k = 0; k < 32; ++k) {
        float4 w = *(float4*)&Ws[k][c4];
        #pragma unroll
        for (int r = 0; r < 4; ++r) {
            float xv = Xs[rt + r][k];
            accv[r].x += xv * w.x; accv[r].y += xv * w.y;
            accv[r].z += xv * w.z; accv[r].w += xv * w.w;
        }
    }
    float4 be4 = *(const float4*)&be[c4];
    #pragma unroll
    for (int r = 0; r < 4; ++r) {
        int row = r0b + rt + r;
        if (row < N_NODES) {
            float dg = (float)(rowp[row + 1] - rowp[row]);
            accv[r].x += dg * be4.x; accv[r].y += dg * be4.y;
            accv[r].z += dg * be4.z; accv[r].w += dg * be4.w;
            *(float4*)&acc[row * 128 + c4] = accv[r];
        }
    }
}

// ---------------------------------------------------------------------------
// acc[d] += sum over CSR edges of h_bf16[src]
// one WAVE (64 lanes) per node; lane covers cols (2*lane, 2*lane+1);
// 4-deep index prefetch + 4 independent partial sums for MLP
// ---------------------------------------------------------------------------
__global__ __launch_bounds__(256) void gather_kernel(
        const uint32* __restrict__ h32,      // 64 uints (=128 bf16) per row
        const int* __restrict__ rowp, const int* __restrict__ csr_src,
        float* __restrict__ acc) {
    int node = blockIdx.x * 4 + (threadIdx.x >> 6);
    if (node >= N_NODES) return;
    int lane = threadIdx.x & 63;
    int beg = rowp[node], end = rowp[node + 1];
    float sx0 = 0.f, sy0 = 0.f, sx1 = 0.f, sy1 = 0.f;
    float sx2 = 0.f, sy2 = 0.f, sx3 = 0.f, sy3 = 0.f;
    int p = beg;
    for (; p + 4 <= end; p += 4) {
        int i0 = csr_src[p], i1 = csr_src[p + 1];
        int i2 = csr_src[p + 2], i3 = csr_src[p + 3];
        uint32 v0 = h32[i0 * 64 + lane];
        uint32 v1 = h32[i1 * 64 + lane];
        uint32 v2 = h32[i2 * 64 + lane];
        uint32 v3 = h32[i3 * 64 + lane];
        sx0 += __uint_as_float(v0 << 16); sy0 += __uint_as_float(v0 & 0xffff0000u);
        sx1 += __uint_as_float(v1 << 16); sy1 += __uint_as_float(v1 & 0xffff0000u);
        sx2 += __uint_as_float(v2 << 16); sy2 += __uint_as_float(v2 & 0xffff0000u);
        sx3 += __uint_as_float(v3 << 16); sy3 += __uint_as_float(v3 & 0xffff0000u);
    }
    for (; p < end; ++p) {
        uint32 v = h32[csr_src[p] * 64 + lane];
        sx0 += __uint_as_float(v << 16); sy0 += __uint_as_float(v & 0xffff0000u);
    }
    float2* ap = (float2*)&acc[node * 128 + lane * 2];
    float2 a = *ap;
    a.x += (sx0 + sx1) + (sx2 + sx3);
    a.y += (sy0 + sy1) + (sy2 + sy3);
    *ap = a;
}

// per-column sum / sumsq over all nodes
__global__ void stats_kernel(const float* __restrict__ acc,
                             float* __restrict__ cs, float* __restrict__ cq) {
    int c = threadIdx.x & 127;
    int rg = threadIdx.x >> 7;
    float s = 0.f, q = 0.f;
    for (int r = blockIdx.x * 2 + rg; r < N_NODES; r += gridDim.x * 2) {
        float v = acc[r * 128 + c];
        s += v; q += v * v;
    }
    unsafeAtomicAdd(&cs[c], s);
    unsafeAtomicAdd(&cq[c], q);
}

// scale/shift from column stats: y = x*scale[c] + shift[c]
__global__ void prep_bn_kernel(const float* __restrict__ cs, const float* __restrict__ cq,
                               const float* __restrict__ gamma, const float* __restrict__ beta,
                               float* __restrict__ scale, float* __restrict__ shift) {
    int c = threadIdx.x;
    const float invN = 1.0f / (float)N_NODES;
    float m = cs[c] * invN;
    float var = cq[c] * invN - m * m;
    float sc = gamma[c] * rsqrtf(var + BN_EPS);
    scale[c] = sc;
    shift[c] = beta[c] - m * sc;
}

// ---------------------------------------------------------------------------
// One block per graph (batch is sorted): binary-search node range, apply
// layer-3 BN+ReLU inline, mean-pool, then the 128->2 FC. No atomics.
// ---------------------------------------------------------------------------
__global__ __launch_bounds__(256) void pool_fc_kernel(
        const float* __restrict__ acc,
        const float* __restrict__ scale, const float* __restrict__ shift,
        const int* __restrict__ batch,
        const float* __restrict__ Wfc, const float* __restrict__ bfc,
        float* __restrict__ out) {
    __shared__ float ps[256];
    int g = blockIdx.x;
    int lo = 0, hi = N_NODES;
    while (lo < hi) { int mid = (lo + hi) >> 1; if (batch[mid] < g) lo = mid + 1; else hi = mid; }
    int start = lo;
    hi = N_NODES;
    while (lo < hi) { int mid = (lo + hi) >> 1; if (batch[mid] < g + 1) lo = mid + 1; else hi = mid; }
    int end = lo;

    int c = threadIdx.x & 127;
    int half = threadIdx.x >> 7;
    float sc = scale[c], sh = shift[c];
    float s = 0.f;
    for (int r = start + half; r < end; r += 2)
        s += fmaxf(0.f, acc[r * 128 + c] * sc + sh);
    ps[threadIdx.x] = s;
    __syncthreads();
    if (half == 0)
        ps[c] = (ps[c] + ps[c + 128]) / fmaxf((float)(end - start), 1.0f);
    __syncthreads();
    if (threadIdx.x < 2) {
        int o = threadIdx.x;
        float t = 0.f;
        #pragma unroll 16
        for (int cc = 0; cc < 128; ++cc) t += ps[cc] * Wfc[cc * 2 + o];
        out[g * 2 + o] = t + bfc[o];
    }
}

// ---------------------------------------------------------------------------
extern "C" void kernel_launch(void* const* d_in, const int* in_sizes, int n_in,
                              void* d_out, int out_size, void* d_ws, size_t ws_size,
                              hipStream_t stream) {
    const float* x         = (const float*)d_in[0];
    const float* edge_attr = (const float*)d_in[1];
    const int*   eidx      = (const int*)d_in[2];
    const int*   batch     = (const int*)d_in[3];
    const float* Wn[3]  = {(const float*)d_in[4],  (const float*)d_in[8],  (const float*)d_in[12]};
    const float* bnb[3] = {(const float*)d_in[5],  (const float*)d_in[9],  (const float*)d_in[13]};
    const float* We[3]  = {(const float*)d_in[6],  (const float*)d_in[10], (const float*)d_in[14]};
    const float* be[3]  = {(const float*)d_in[7],  (const float*)d_in[11], (const float*)d_in[15]};
    const float* gm[3]  = {(const float*)d_in[16], (const float*)d_in[18], (const float*)d_in[20]};
    const float* bt[3]  = {(const float*)d_in[17], (const float*)d_in[19], (const float*)d_in[21]};
    const float* Wfc = (const float*)d_in[22];
    const float* bfc = (const float*)d_in[23];
    float* out = (float*)d_out;

    char* p = (char*)d_ws;
    auto alloc = [&](size_t bytes) {
        char* q = p;
        p += (bytes + 255) & ~size_t(255);
        return q;
    };
    float*    Ea     = (float*)alloc(sizeof(float) * N_NODES * EDGE_DIM);
    ushort16* hbuf   = (ushort16*)alloc(sizeof(ushort16) * N_NODES * HID);
    float*    accA   = (float*)alloc(sizeof(float) * N_NODES * HID);
    float*    accB   = (float*)alloc(sizeof(float) * N_NODES * HID);
    float*    cs     = (float*)alloc(sizeof(float) * HID);    // cs and cq contiguous
    float*    cq     = (float*)alloc(sizeof(float) * HID);
    float*    scale  = (float*)alloc(sizeof(float) * HID);
    float*    shift  = (float*)alloc(sizeof(float) * HID);
    int*      deg    = (int*)alloc(sizeof(int) * N_NODES);
    int*      rowp   = (int*)alloc(sizeof(int) * (N_NODES + 1));
    int*      cursor = (int*)alloc(sizeof(int) * N_NODES);
    int*      csr    = (int*)alloc(sizeof(int) * N_EDGES);
    int*      csre   = (int*)alloc(sizeof(int) * N_EDGES);

    // zero all accumulation buffers every call (harness does not re-poison)
    hipMemsetAsync(deg, 0, sizeof(int) * N_NODES, stream);
    hipMemsetAsync(cursor, 0, sizeof(int) * N_NODES, stream);

    deg_hist_kernel<<<(N_EDGES + 255) / 256, 256, 0, stream>>>(eidx, deg);
    scan_kernel<<<1, 1024, 0, stream>>>(deg, rowp);
    fill_csr_kernel<<<(N_EDGES + 255) / 256, 256, 0, stream>>>(eidx, rowp, cursor, csr, csre);
    ea_gather_kernel<<<(N_NODES + 7) / 8, 256, 0, stream>>>(edge_attr, rowp, csre, Ea);

    float* accs[3] = {accA, accB, accA};
    const int ngrid = (N_NODES + 31) / 32;
    const float* X = x;
    for (int l = 0; l < 3; ++l) {
        hipMemsetAsync(cs, 0, sizeof(float) * HID * 2, stream);  // cs + cq
        float* acc = accs[l];
        if (l == 0) {
            gemm_base_kernel<false><<<ngrid, 256, 0, stream>>>(
                X, Wn[l], bnb[l], Ea, We[l], be[l], rowp, nullptr, nullptr, hbuf, acc);
        } else {
            gemm_base_kernel<true><<<ngrid, 256, 0, stream>>>(
                X, Wn[l], bnb[l], Ea, We[l], be[l], rowp, scale, shift, hbuf, acc);
        }
        gather_kernel<<<(N_NODES + 3) / 4, 256, 0, stream>>>(
            (const uint32*)hbuf, rowp, csr, acc);
        stats_kernel<<<256, 256, 0, stream>>>(acc, cs, cq);
        prep_bn_kernel<<<1, 128, 0, stream>>>(cs, cq, gm[l], bt[l], scale, shift);
        X = acc;
    }
    pool_fc_kernel<<<NUM_GRAPHS, 256, 0, stream>>>(
        accs[2], scale, shift, batch, Wfc, bfc, out);
}

// Round 5
// 527.681 us; speedup vs baseline: 1.8566x; 1.2106x over previous
//
#include <hip/hip_runtime.h>

#define N_NODES 50000
#define N_EDGES 640000
#define HID 128
#define EDGE_DIM 32
#define NUM_GRAPHS 512
#define BN_EPS 1e-5f
#define NGROUPS 6250   // ceil(N_NODES/8)
#define NSCB 49        // ceil(N_NODES/1024)

typedef unsigned int uint32;
typedef unsigned short ushort16;

// round-to-nearest-even f32 -> bf16 bits
__device__ inline ushort16 f2bf(float x) {
    uint32 u = __float_as_uint(x);
    return (ushort16)((u + 0x7fff + ((u >> 16) & 1)) >> 16);
}

// ---------------------------------------------------------------------------
// deg[d] = number of edges with dst == d
// ---------------------------------------------------------------------------
__global__ void deg_hist_kernel(const int* __restrict__ eidx, int* __restrict__ deg) {
    int e = blockIdx.x * 256 + threadIdx.x;
    if (e >= N_EDGES) return;
    atomicAdd(&deg[eidx[N_EDGES + e]], 1);
}

// ---------------------------------------------------------------------------
// Parallel exclusive scan of deg -> rowp, 3 dispatches
// ---------------------------------------------------------------------------
__global__ void scan_part1_kernel(const int* __restrict__ deg, int* __restrict__ bsum) {
    __shared__ int ts[256];
    int tid = threadIdx.x;
    int base = blockIdx.x * 1024 + tid * 4;
    int s = 0;
    #pragma unroll
    for (int j = 0; j < 4; ++j) { int i = base + j; if (i < N_NODES) s += deg[i]; }
    ts[tid] = s;
    __syncthreads();
    for (int off = 128; off > 0; off >>= 1) {
        if (tid < off) ts[tid] += ts[tid + off];
        __syncthreads();
    }
    if (tid == 0) bsum[blockIdx.x] = ts[0];
}

__global__ void scan_part2_kernel(const int* __restrict__ bsum, int* __restrict__ boff) {
    __shared__ int b[64];
    int t = threadIdx.x;
    b[t] = (t < NSCB) ? bsum[t] : 0;
    __syncthreads();
    if (t == 0) {
        int run = 0;
        for (int i = 0; i < NSCB; ++i) { int x = b[i]; b[i] = run; run += x; }
    }
    __syncthreads();
    if (t < NSCB) boff[t] = b[t];
}

__global__ void scan_part3_kernel(const int* __restrict__ deg, const int* __restrict__ boff,
                                  int* __restrict__ rowp) {
    __shared__ int ts[256];
    int tid = threadIdx.x;
    int base = blockIdx.x * 1024 + tid * 4;
    int v[4];
    int s = 0;
    #pragma unroll
    for (int j = 0; j < 4; ++j) {
        int i = base + j;
        v[j] = (i < N_NODES) ? deg[i] : 0;
        s += v[j];
    }
    ts[tid] = s;
    __syncthreads();
    for (int off = 1; off < 256; off <<= 1) {
        int t = (tid >= off) ? ts[tid - off] : 0;
        __syncthreads();
        ts[tid] += t;
        __syncthreads();
    }
    int excl = boff[blockIdx.x] + ts[tid] - s;
    #pragma unroll
    for (int j = 0; j < 4; ++j) {
        int i = base + j;
        if (i < N_NODES) rowp[i] = excl;
        excl += v[j];
    }
    if (blockIdx.x == 0 && tid == 0) rowp[N_NODES] = N_EDGES;
}

// CSR fill: csr_src[p] = source node, csr_eid[p] = edge id
__global__ void fill_csr_kernel(const int* __restrict__ eidx,
                                const int* __restrict__ rowp,
                                int* __restrict__ cursor,
                                int* __restrict__ csr_src,
                                int* __restrict__ csr_eid) {
    int e = blockIdx.x * 256 + threadIdx.x;
    if (e >= N_EDGES) return;
    int d = eidx[N_EDGES + e];
    int pos = rowp[d] + atomicAdd(&cursor[d], 1);
    csr_src[pos] = eidx[e];
    csr_eid[pos] = e;
}

// Ea[d] = sum of edge_attr rows with dst == d (CSR gather, no float atomics)
__global__ void ea_gather_kernel(const float* __restrict__ edge_attr,
                                 const int* __restrict__ rowp,
                                 const int* __restrict__ csr_eid,
                                 float* __restrict__ Ea) {
    int node = blockIdx.x * 8 + (threadIdx.x >> 5);
    int c = threadIdx.x & 31;
    if (node >= N_NODES) return;
    int beg = rowp[node], end = rowp[node + 1];
    float s = 0.f;
    for (int p = beg; p < end; ++p)
        s += edge_attr[csr_eid[p] * EDGE_DIM + c];
    Ea[node * EDGE_DIM + c] = s;
}

// ---------------------------------------------------------------------------
// W-resident streaming GEMM. Per layer:
//   xin    = BN ? relu(X*scale + shift) : X
//   h[i]   = xin[i] @ Wn + bn      -> bf16 (gather operand)
//   acc[i] = h[i] + Ea[i] @ We + deg[i] * be   -> fp32
// 1024 threads = 16 waves; Wn resident in LDS (loaded once per block);
// each wave independently streams 8-row groups (no barriers in main loop,
// wave-private Xs slice). Lane owns column pair (2*lane, 2*lane+1).
// LDS: 64K (Wn) + 64K (Xs) + 1K (scale/shift) = 129 KB -> 1 block/CU.
// We (16 KB) is read straight from L2 in the short K=32 edge phase.
// ---------------------------------------------------------------------------
template <bool BN>
__global__ __launch_bounds__(1024) void gemm_stream_kernel(
        const float* __restrict__ X, const float* __restrict__ Wn,
        const float* __restrict__ bnb,
        const float* __restrict__ Ea, const float* __restrict__ We,
        const float* __restrict__ be, const int* __restrict__ deg,
        const float* __restrict__ scale, const float* __restrict__ shift,
        uint32* __restrict__ hb32, float* __restrict__ acc) {
    __shared__ __align__(16) float Wns[128 * 128];   // [k][c], 64 KB
    __shared__ __align__(16) float Xs[16][8][128];   // per-wave row staging, 64 KB
    __shared__ __align__(16) float scs[128];
    __shared__ __align__(16) float shs[128];
    int tid = threadIdx.x;

    #pragma unroll
    for (int j = 0; j < 4; ++j)
        ((float4*)Wns)[tid + j * 1024] = ((const float4*)Wn)[tid + j * 1024];
    if (BN && tid < 32) {
        ((float4*)scs)[tid] = ((const float4*)scale)[tid];
        ((float4*)shs)[tid] = ((const float4*)shift)[tid];
    }
    __syncthreads();

    int wid = tid >> 6, lane = tid & 63;
    int half = lane >> 5, c4 = (lane & 31) * 4;
    float2 bn2 = *(const float2*)&bnb[lane * 2];
    float2 be2 = *(const float2*)&be[lane * 2];

    for (int g = blockIdx.x * 16 + wid; g < NGROUPS; g += gridDim.x * 16) {
        int r0 = g * 8;
        // stage 8 rows (wave-private slice; in-wave LDS ordering, no barrier)
        #pragma unroll
        for (int i = 0; i < 4; ++i) {
            int row = r0 + i * 2 + half;
            int rc = min(row, N_NODES - 1);
            float4 v = *(const float4*)&X[rc * 128 + c4];
            if (BN) {
                float4 s4 = *(const float4*)&scs[c4];
                float4 h4 = *(const float4*)&shs[c4];
                v.x = fmaxf(0.f, v.x * s4.x + h4.x);
                v.y = fmaxf(0.f, v.y * s4.y + h4.y);
                v.z = fmaxf(0.f, v.z * s4.z + h4.z);
                v.w = fmaxf(0.f, v.w * s4.w + h4.w);
            }
            *(float4*)&Xs[wid][i * 2 + half][c4] = v;
        }
        float2 a[8];
        #pragma unroll
        for (int r = 0; r < 8; ++r) a[r] = make_float2(0.f, 0.f);
        // ---- node GEMM: K = 128 over LDS-resident Wn ----
        #pragma unroll 2
        for (int k = 0; k < 128; ++k) {
            float2 w = *(const float2*)&Wns[k * 128 + lane * 2];
            #pragma unroll
            for (int r = 0; r < 8; ++r) {
                float xv = Xs[wid][r][k];
                a[r].x = fmaf(xv, w.x, a[r].x);
                a[r].y = fmaf(xv, w.y, a[r].y);
            }
        }
        #pragma unroll
        for (int r = 0; r < 8; ++r) { a[r].x += bn2.x; a[r].y += bn2.y; }
        #pragma unroll
        for (int r = 0; r < 8; ++r) {
            int row = r0 + r;
            if (row < N_NODES)
                hb32[row * 64 + lane] =
                    (uint32)f2bf(a[r].x) | ((uint32)f2bf(a[r].y) << 16);
        }
        // ---- edge GEMM: K = 32, We from L2 ----
        {
            int er = lane >> 3, ec = (lane & 7) * 4;
            int rc = min(r0 + er, N_NODES - 1);
            *(float4*)&Xs[wid][er][ec] = *(const float4*)&Ea[rc * 32 + ec];
        }
        #pragma unroll 2
        for (int k = 0; k < 32; ++k) {
            float2 w = *(const float2*)&We[k * 128 + lane * 2];
            #pragma unroll
            for (int r = 0; r < 8; ++r) {
                float xv = Xs[wid][r][k];
                a[r].x = fmaf(xv, w.x, a[r].x);
                a[r].y = fmaf(xv, w.y, a[r].y);
            }
        }
        #pragma unroll
        for (int r = 0; r < 8; ++r) {
            int row = r0 + r;
            if (row < N_NODES) {
                float dg = (float)deg[row];
                float2 o;
                o.x = a[r].x + dg * be2.x;
                o.y = a[r].y + dg * be2.y;
                *(float2*)&acc[row * 128 + lane * 2] = o;
            }
        }
    }
}

// ---------------------------------------------------------------------------
// acc[d] += sum over CSR edges of h_bf16[src]
// one WAVE (64 lanes) per node; lane covers cols (2*lane, 2*lane+1);
// 4-deep index prefetch + 4 independent partial sums for MLP
// ---------------------------------------------------------------------------
__global__ __launch_bounds__(256) void gather_kernel(
        const uint32* __restrict__ h32,      // 64 uints (=128 bf16) per row
        const int* __restrict__ rowp, const int* __restrict__ csr_src,
        float* __restrict__ acc) {
    int node = blockIdx.x * 4 + (threadIdx.x >> 6);
    if (node >= N_NODES) return;
    int lane = threadIdx.x & 63;
    int beg = rowp[node], end = rowp[node + 1];
    float sx0 = 0.f, sy0 = 0.f, sx1 = 0.f, sy1 = 0.f;
    float sx2 = 0.f, sy2 = 0.f, sx3 = 0.f, sy3 = 0.f;
    int p = beg;
    for (; p + 4 <= end; p += 4) {
        int i0 = csr_src[p], i1 = csr_src[p + 1];
        int i2 = csr_src[p + 2], i3 = csr_src[p + 3];
        uint32 v0 = h32[i0 * 64 + lane];
        uint32 v1 = h32[i1 * 64 + lane];
        uint32 v2 = h32[i2 * 64 + lane];
        uint32 v3 = h32[i3 * 64 + lane];
        sx0 += __uint_as_float(v0 << 16); sy0 += __uint_as_float(v0 & 0xffff0000u);
        sx1 += __uint_as_float(v1 << 16); sy1 += __uint_as_float(v1 & 0xffff0000u);
        sx2 += __uint_as_float(v2 << 16); sy2 += __uint_as_float(v2 & 0xffff0000u);
        sx3 += __uint_as_float(v3 << 16); sy3 += __uint_as_float(v3 & 0xffff0000u);
    }
    for (; p < end; ++p) {
        uint32 v = h32[csr_src[p] * 64 + lane];
        sx0 += __uint_as_float(v << 16); sy0 += __uint_as_float(v & 0xffff0000u);
    }
    float2* ap = (float2*)&acc[node * 128 + lane * 2];
    float2 a = *ap;
    a.x += (sx0 + sx1) + (sx2 + sx3);
    a.y += (sy0 + sy1) + (sy2 + sy3);
    *ap = a;
}

// per-column sum / sumsq over all nodes
__global__ void stats_kernel(const float* __restrict__ acc,
                             float* __restrict__ cs, float* __restrict__ cq) {
    int c = threadIdx.x & 127;
    int rg = threadIdx.x >> 7;
    float s = 0.f, q = 0.f;
    for (int r = blockIdx.x * 2 + rg; r < N_NODES; r += gridDim.x * 2) {
        float v = acc[r * 128 + c];
        s += v; q += v * v;
    }
    unsafeAtomicAdd(&cs[c], s);
    unsafeAtomicAdd(&cq[c], q);
}

// scale/shift from column stats: y = x*scale[c] + shift[c]
__global__ void prep_bn_kernel(const float* __restrict__ cs, const float* __restrict__ cq,
                               const float* __restrict__ gamma, const float* __restrict__ beta,
                               float* __restrict__ scale, float* __restrict__ shift) {
    int c = threadIdx.x;
    const float invN = 1.0f / (float)N_NODES;
    float m = cs[c] * invN;
    float var = cq[c] * invN - m * m;
    float sc = gamma[c] * rsqrtf(var + BN_EPS);
    scale[c] = sc;
    shift[c] = beta[c] - m * sc;
}

// ---------------------------------------------------------------------------
// One block per graph (batch is sorted): binary-search node range, apply
// layer-3 BN+ReLU inline, mean-pool, then the 128->2 FC. No atomics.
// ---------------------------------------------------------------------------
__global__ __launch_bounds__(256) void pool_fc_kernel(
        const float* __restrict__ acc,
        const float* __restrict__ scale, const float* __restrict__ shift,
        const int* __restrict__ batch,
        const float* __restrict__ Wfc, const float* __restrict__ bfc,
        float* __restrict__ out) {
    __shared__ float ps[256];
    int g = blockIdx.x;
    int lo = 0, hi = N_NODES;
    while (lo < hi) { int mid = (lo + hi) >> 1; if (batch[mid] < g) lo = mid + 1; else hi = mid; }
    int start = lo;
    hi = N_NODES;
    while (lo < hi) { int mid = (lo + hi) >> 1; if (batch[mid] < g + 1) lo = mid + 1; else hi = mid; }
    int end = lo;

    int c = threadIdx.x & 127;
    int half = threadIdx.x >> 7;
    float sc = scale[c], sh = shift[c];
    float s = 0.f;
    for (int r = start + half; r < end; r += 2)
        s += fmaxf(0.f, acc[r * 128 + c] * sc + sh);
    ps[threadIdx.x] = s;
    __syncthreads();
    if (half == 0)
        ps[c] = (ps[c] + ps[c + 128]) / fmaxf((float)(end - start), 1.0f);
    __syncthreads();
    if (threadIdx.x < 2) {
        int o = threadIdx.x;
        float t = 0.f;
        #pragma unroll 16
        for (int cc = 0; cc < 128; ++cc) t += ps[cc] * Wfc[cc * 2 + o];
        out[g * 2 + o] = t + bfc[o];
    }
}

// ---------------------------------------------------------------------------
extern "C" void kernel_launch(void* const* d_in, const int* in_sizes, int n_in,
                              void* d_out, int out_size, void* d_ws, size_t ws_size,
                              hipStream_t stream) {
    const float* x         = (const float*)d_in[0];
    const float* edge_attr = (const float*)d_in[1];
    const int*   eidx      = (const int*)d_in[2];
    const int*   batch     = (const int*)d_in[3];
    const float* Wn[3]  = {(const float*)d_in[4],  (const float*)d_in[8],  (const float*)d_in[12]};
    const float* bnb[3] = {(const float*)d_in[5],  (const float*)d_in[9],  (const float*)d_in[13]};
    const float* We[3]  = {(const float*)d_in[6],  (const float*)d_in[10], (const float*)d_in[14]};
    const float* be[3]  = {(const float*)d_in[7],  (const float*)d_in[11], (const float*)d_in[15]};
    const float* gm[3]  = {(const float*)d_in[16], (const float*)d_in[18], (const float*)d_in[20]};
    const float* bt[3]  = {(const float*)d_in[17], (const float*)d_in[19], (const float*)d_in[21]};
    const float* Wfc = (const float*)d_in[22];
    const float* bfc = (const float*)d_in[23];
    float* out = (float*)d_out;

    char* p = (char*)d_ws;
    auto alloc = [&](size_t bytes) {
        char* q = p;
        p += (bytes + 255) & ~size_t(255);
        return q;
    };
    float*  Ea     = (float*)alloc(sizeof(float) * N_NODES * EDGE_DIM);
    uint32* hbuf   = (uint32*)alloc(sizeof(uint32) * N_NODES * 64);   // bf16x2 packed
    float*  accA   = (float*)alloc(sizeof(float) * N_NODES * HID);
    float*  accB   = (float*)alloc(sizeof(float) * N_NODES * HID);
    float*  cs     = (float*)alloc(sizeof(float) * HID);    // cs and cq contiguous
    float*  cq     = (float*)alloc(sizeof(float) * HID);
    float*  scale  = (float*)alloc(sizeof(float) * HID);
    float*  shift  = (float*)alloc(sizeof(float) * HID);
    int*    deg    = (int*)alloc(sizeof(int) * N_NODES);
    int*    rowp   = (int*)alloc(sizeof(int) * (N_NODES + 1));
    int*    cursor = (int*)alloc(sizeof(int) * N_NODES);
    int*    csr    = (int*)alloc(sizeof(int) * N_EDGES);
    int*    csre   = (int*)alloc(sizeof(int) * N_EDGES);
    int*    bsum   = (int*)alloc(sizeof(int) * 64);
    int*    boff   = (int*)alloc(sizeof(int) * 64);

    // zero all accumulation buffers every call (harness does not re-poison)
    hipMemsetAsync(deg, 0, sizeof(int) * N_NODES, stream);
    hipMemsetAsync(cursor, 0, sizeof(int) * N_NODES, stream);

    deg_hist_kernel<<<(N_EDGES + 255) / 256, 256, 0, stream>>>(eidx, deg);
    scan_part1_kernel<<<NSCB, 256, 0, stream>>>(deg, bsum);
    scan_part2_kernel<<<1, 64, 0, stream>>>(bsum, boff);
    scan_part3_kernel<<<NSCB, 256, 0, stream>>>(deg, boff, rowp);
    fill_csr_kernel<<<(N_EDGES + 255) / 256, 256, 0, stream>>>(eidx, rowp, cursor, csr, csre);
    ea_gather_kernel<<<(N_NODES + 7) / 8, 256, 0, stream>>>(edge_attr, rowp, csre, Ea);

    float* accs[3] = {accA, accB, accA};
    const float* X = x;
    for (int l = 0; l < 3; ++l) {
        hipMemsetAsync(cs, 0, sizeof(float) * HID * 2, stream);  // cs + cq
        float* acc = accs[l];
        if (l == 0) {
            gemm_stream_kernel<false><<<256, 1024, 0, stream>>>(
                X, Wn[l], bnb[l], Ea, We[l], be[l], deg, nullptr, nullptr, hbuf, acc);
        } else {
            gemm_stream_kernel<true><<<256, 1024, 0, stream>>>(
                X, Wn[l], bnb[l], Ea, We[l], be[l], deg, scale, shift, hbuf, acc);
        }
        gather_kernel<<<(N_NODES + 3) / 4, 256, 0, stream>>>(
            hbuf, rowp, csr, acc);
        stats_kernel<<<256, 256, 0, stream>>>(acc, cs, cq);
        prep_bn_kernel<<<1, 128, 0, stream>>>(cs, cq, gm[l], bt[l], scale, shift);
        X = acc;
    }
    pool_fc_kernel<<<NUM_GRAPHS, 256, 0, stream>>>(
        accs[2], scale, shift, batch, Wfc, bfc, out);
}

// Round 6
// 511.624 us; speedup vs baseline: 1.9149x; 1.0314x over previous
//
#include <hip/hip_runtime.h>

#define N_NODES 50000
#define N_EDGES 640000
#define HID 128
#define EDGE_DIM 32
#define NUM_GRAPHS 512
#define BN_EPS 1e-5f
#define NGROUPS 6250   // ceil(N_NODES/8)
#define NSCB 49        // ceil(N_NODES/1024)

typedef unsigned int uint32;
typedef unsigned short ushort16;

// round-to-nearest-even f32 -> bf16 bits
__device__ inline ushort16 f2bf(float x) {
    uint32 u = __float_as_uint(x);
    return (ushort16)((u + 0x7fff + ((u >> 16) & 1)) >> 16);
}

// ---------------------------------------------------------------------------
// deg[d] = number of edges with dst == d
// ---------------------------------------------------------------------------
__global__ void deg_hist_kernel(const int* __restrict__ eidx, int* __restrict__ deg) {
    int e = blockIdx.x * 256 + threadIdx.x;
    if (e >= N_EDGES) return;
    atomicAdd(&deg[eidx[N_EDGES + e]], 1);
}

// ---------------------------------------------------------------------------
// Parallel exclusive scan of deg -> rowp, 3 dispatches
// ---------------------------------------------------------------------------
__global__ void scan_part1_kernel(const int* __restrict__ deg, int* __restrict__ bsum) {
    __shared__ int ts[256];
    int tid = threadIdx.x;
    int base = blockIdx.x * 1024 + tid * 4;
    int s = 0;
    #pragma unroll
    for (int j = 0; j < 4; ++j) { int i = base + j; if (i < N_NODES) s += deg[i]; }
    ts[tid] = s;
    __syncthreads();
    for (int off = 128; off > 0; off >>= 1) {
        if (tid < off) ts[tid] += ts[tid + off];
        __syncthreads();
    }
    if (tid == 0) bsum[blockIdx.x] = ts[0];
}

__global__ void scan_part2_kernel(const int* __restrict__ bsum, int* __restrict__ boff) {
    __shared__ int b[64];
    int t = threadIdx.x;
    b[t] = (t < NSCB) ? bsum[t] : 0;
    __syncthreads();
    if (t == 0) {
        int run = 0;
        for (int i = 0; i < NSCB; ++i) { int x = b[i]; b[i] = run; run += x; }
    }
    __syncthreads();
    if (t < NSCB) boff[t] = b[t];
}

__global__ void scan_part3_kernel(const int* __restrict__ deg, const int* __restrict__ boff,
                                  int* __restrict__ rowp) {
    __shared__ int ts[256];
    int tid = threadIdx.x;
    int base = blockIdx.x * 1024 + tid * 4;
    int v[4];
    int s = 0;
    #pragma unroll
    for (int j = 0; j < 4; ++j) {
        int i = base + j;
        v[j] = (i < N_NODES) ? deg[i] : 0;
        s += v[j];
    }
    ts[tid] = s;
    __syncthreads();
    for (int off = 1; off < 256; off <<= 1) {
        int t = (tid >= off) ? ts[tid - off] : 0;
        __syncthreads();
        ts[tid] += t;
        __syncthreads();
    }
    int excl = boff[blockIdx.x] + ts[tid] - s;
    #pragma unroll
    for (int j = 0; j < 4; ++j) {
        int i = base + j;
        if (i < N_NODES) rowp[i] = excl;
        excl += v[j];
    }
    if (blockIdx.x == 0 && tid == 0) rowp[N_NODES] = N_EDGES;
}

// CSR fill: csr_src[p] = source node, csr_eid[p] = edge id
__global__ void fill_csr_kernel(const int* __restrict__ eidx,
                                const int* __restrict__ rowp,
                                int* __restrict__ cursor,
                                int* __restrict__ csr_src,
                                int* __restrict__ csr_eid) {
    int e = blockIdx.x * 256 + threadIdx.x;
    if (e >= N_EDGES) return;
    int d = eidx[N_EDGES + e];
    int pos = rowp[d] + atomicAdd(&cursor[d], 1);
    csr_src[pos] = eidx[e];
    csr_eid[pos] = e;
}

// ---------------------------------------------------------------------------
// Ea[d] = sum of edge_attr rows with dst == d (CSR gather, no float atomics)
// half-wave (32 lanes) per node, 4-deep index prefetch + 4 independent
// accumulators for memory-level parallelism (latency-bound random rows)
// ---------------------------------------------------------------------------
__global__ __launch_bounds__(256) void ea_gather_kernel(
        const float* __restrict__ edge_attr,
        const int* __restrict__ rowp,
        const int* __restrict__ csr_eid,
        float* __restrict__ Ea) {
    int node = blockIdx.x * 8 + (threadIdx.x >> 5);
    int c = threadIdx.x & 31;
    if (node >= N_NODES) return;
    int beg = rowp[node], end = rowp[node + 1];
    float s0 = 0.f, s1 = 0.f, s2 = 0.f, s3 = 0.f;
    int p = beg;
    for (; p + 4 <= end; p += 4) {
        int e0 = csr_eid[p],     e1 = csr_eid[p + 1];
        int e2 = csr_eid[p + 2], e3 = csr_eid[p + 3];
        s0 += edge_attr[e0 * EDGE_DIM + c];
        s1 += edge_attr[e1 * EDGE_DIM + c];
        s2 += edge_attr[e2 * EDGE_DIM + c];
        s3 += edge_attr[e3 * EDGE_DIM + c];
    }
    for (; p < end; ++p)
        s0 += edge_attr[csr_eid[p] * EDGE_DIM + c];
    Ea[node * EDGE_DIM + c] = (s0 + s1) + (s2 + s3);
}

// ---------------------------------------------------------------------------
// W-resident streaming GEMM. Per layer:
//   xin    = BN ? relu(X*scale + shift) : X
//   h[i]   = xin[i] @ Wn + bn      -> bf16 (gather operand)
//   acc[i] = h[i] + Ea[i] @ We + deg[i] * be   -> fp32
// 1024 threads = 16 waves; Wn resident in LDS (loaded once per block);
// each wave independently streams 8-row groups (no barriers in main loop,
// wave-private Xs slice). Lane owns column pair (2*lane, 2*lane+1).
// LDS: 64K (Wn) + 64K (Xs) + 1K (scale/shift) = 129 KB -> 1 block/CU.
// We (16 KB) is read straight from L2 in the short K=32 edge phase.
// ---------------------------------------------------------------------------
template <bool BN>
__global__ __launch_bounds__(1024) void gemm_stream_kernel(
        const float* __restrict__ X, const float* __restrict__ Wn,
        const float* __restrict__ bnb,
        const float* __restrict__ Ea, const float* __restrict__ We,
        const float* __restrict__ be, const int* __restrict__ deg,
        const float* __restrict__ scale, const float* __restrict__ shift,
        uint32* __restrict__ hb32, float* __restrict__ acc) {
    __shared__ __align__(16) float Wns[128 * 128];   // [k][c], 64 KB
    __shared__ __align__(16) float Xs[16][8][128];   // per-wave row staging, 64 KB
    __shared__ __align__(16) float scs[128];
    __shared__ __align__(16) float shs[128];
    int tid = threadIdx.x;

    #pragma unroll
    for (int j = 0; j < 4; ++j)
        ((float4*)Wns)[tid + j * 1024] = ((const float4*)Wn)[tid + j * 1024];
    if (BN && tid < 32) {
        ((float4*)scs)[tid] = ((const float4*)scale)[tid];
        ((float4*)shs)[tid] = ((const float4*)shift)[tid];
    }
    __syncthreads();

    int wid = tid >> 6, lane = tid & 63;
    int half = lane >> 5, c4 = (lane & 31) * 4;
    float2 bn2 = *(const float2*)&bnb[lane * 2];
    float2 be2 = *(const float2*)&be[lane * 2];

    for (int g = blockIdx.x * 16 + wid; g < NGROUPS; g += gridDim.x * 16) {
        int r0 = g * 8;
        // stage 8 rows (wave-private slice; in-wave LDS ordering, no barrier)
        #pragma unroll
        for (int i = 0; i < 4; ++i) {
            int row = r0 + i * 2 + half;
            int rc = min(row, N_NODES - 1);
            float4 v = *(const float4*)&X[rc * 128 + c4];
            if (BN) {
                float4 s4 = *(const float4*)&scs[c4];
                float4 h4 = *(const float4*)&shs[c4];
                v.x = fmaxf(0.f, v.x * s4.x + h4.x);
                v.y = fmaxf(0.f, v.y * s4.y + h4.y);
                v.z = fmaxf(0.f, v.z * s4.z + h4.z);
                v.w = fmaxf(0.f, v.w * s4.w + h4.w);
            }
            *(float4*)&Xs[wid][i * 2 + half][c4] = v;
        }
        float2 a[8];
        #pragma unroll
        for (int r = 0; r < 8; ++r) a[r] = make_float2(0.f, 0.f);
        // ---- node GEMM: K = 128 over LDS-resident Wn ----
        #pragma unroll 2
        for (int k = 0; k < 128; ++k) {
            float2 w = *(const float2*)&Wns[k * 128 + lane * 2];
            #pragma unroll
            for (int r = 0; r < 8; ++r) {
                float xv = Xs[wid][r][k];
                a[r].x = fmaf(xv, w.x, a[r].x);
                a[r].y = fmaf(xv, w.y, a[r].y);
            }
        }
        #pragma unroll
        for (int r = 0; r < 8; ++r) { a[r].x += bn2.x; a[r].y += bn2.y; }
        #pragma unroll
        for (int r = 0; r < 8; ++r) {
            int row = r0 + r;
            if (row < N_NODES)
                hb32[row * 64 + lane] =
                    (uint32)f2bf(a[r].x) | ((uint32)f2bf(a[r].y) << 16);
        }
        // ---- edge GEMM: K = 32, We from L2 ----
        {
            int er = lane >> 3, ec = (lane & 7) * 4;
            int rc = min(r0 + er, N_NODES - 1);
            *(float4*)&Xs[wid][er][ec] = *(const float4*)&Ea[rc * 32 + ec];
        }
        #pragma unroll 2
        for (int k = 0; k < 32; ++k) {
            float2 w = *(const float2*)&We[k * 128 + lane * 2];
            #pragma unroll
            for (int r = 0; r < 8; ++r) {
                float xv = Xs[wid][r][k];
                a[r].x = fmaf(xv, w.x, a[r].x);
                a[r].y = fmaf(xv, w.y, a[r].y);
            }
        }
        #pragma unroll
        for (int r = 0; r < 8; ++r) {
            int row = r0 + r;
            if (row < N_NODES) {
                float dg = (float)deg[row];
                float2 o;
                o.x = a[r].x + dg * be2.x;
                o.y = a[r].y + dg * be2.y;
                *(float2*)&acc[row * 128 + lane * 2] = o;
            }
        }
    }
}

// ---------------------------------------------------------------------------
// acc[d] += sum over CSR edges of h_bf16[src]
// one WAVE (64 lanes) per node; lane covers cols (2*lane, 2*lane+1);
// 4-deep index prefetch + 4 independent partial sums for MLP
// ---------------------------------------------------------------------------
__global__ __launch_bounds__(256) void gather_kernel(
        const uint32* __restrict__ h32,      // 64 uints (=128 bf16) per row
        const int* __restrict__ rowp, const int* __restrict__ csr_src,
        float* __restrict__ acc) {
    int node = blockIdx.x * 4 + (threadIdx.x >> 6);
    if (node >= N_NODES) return;
    int lane = threadIdx.x & 63;
    int beg = rowp[node], end = rowp[node + 1];
    float sx0 = 0.f, sy0 = 0.f, sx1 = 0.f, sy1 = 0.f;
    float sx2 = 0.f, sy2 = 0.f, sx3 = 0.f, sy3 = 0.f;
    int p = beg;
    for (; p + 4 <= end; p += 4) {
        int i0 = csr_src[p], i1 = csr_src[p + 1];
        int i2 = csr_src[p + 2], i3 = csr_src[p + 3];
        uint32 v0 = h32[i0 * 64 + lane];
        uint32 v1 = h32[i1 * 64 + lane];
        uint32 v2 = h32[i2 * 64 + lane];
        uint32 v3 = h32[i3 * 64 + lane];
        sx0 += __uint_as_float(v0 << 16); sy0 += __uint_as_float(v0 & 0xffff0000u);
        sx1 += __uint_as_float(v1 << 16); sy1 += __uint_as_float(v1 & 0xffff0000u);
        sx2 += __uint_as_float(v2 << 16); sy2 += __uint_as_float(v2 & 0xffff0000u);
        sx3 += __uint_as_float(v3 << 16); sy3 += __uint_as_float(v3 & 0xffff0000u);
    }
    for (; p < end; ++p) {
        uint32 v = h32[csr_src[p] * 64 + lane];
        sx0 += __uint_as_float(v << 16); sy0 += __uint_as_float(v & 0xffff0000u);
    }
    float2* ap = (float2*)&acc[node * 128 + lane * 2];
    float2 a = *ap;
    a.x += (sx0 + sx1) + (sx2 + sx3);
    a.y += (sy0 + sy1) + (sy2 + sy3);
    *ap = a;
}

// per-column sum / sumsq over all nodes
__global__ void stats_kernel(const float* __restrict__ acc,
                             float* __restrict__ cs, float* __restrict__ cq) {
    int c = threadIdx.x & 127;
    int rg = threadIdx.x >> 7;
    float s = 0.f, q = 0.f;
    for (int r = blockIdx.x * 2 + rg; r < N_NODES; r += gridDim.x * 2) {
        float v = acc[r * 128 + c];
        s += v; q += v * v;
    }
    unsafeAtomicAdd(&cs[c], s);
    unsafeAtomicAdd(&cq[c], q);
}

// scale/shift from column stats: y = x*scale[c] + shift[c]
__global__ void prep_bn_kernel(const float* __restrict__ cs, const float* __restrict__ cq,
                               const float* __restrict__ gamma, const float* __restrict__ beta,
                               float* __restrict__ scale, float* __restrict__ shift) {
    int c = threadIdx.x;
    const float invN = 1.0f / (float)N_NODES;
    float m = cs[c] * invN;
    float var = cq[c] * invN - m * m;
    float sc = gamma[c] * rsqrtf(var + BN_EPS);
    scale[c] = sc;
    shift[c] = beta[c] - m * sc;
}

// ---------------------------------------------------------------------------
// One block per graph (batch is sorted): binary-search node range, apply
// layer-3 BN+ReLU inline, mean-pool, then the 128->2 FC. No atomics.
// ---------------------------------------------------------------------------
__global__ __launch_bounds__(256) void pool_fc_kernel(
        const float* __restrict__ acc,
        const float* __restrict__ scale, const float* __restrict__ shift,
        const int* __restrict__ batch,
        const float* __restrict__ Wfc, const float* __restrict__ bfc,
        float* __restrict__ out) {
    __shared__ float ps[256];
    int g = blockIdx.x;
    int lo = 0, hi = N_NODES;
    while (lo < hi) { int mid = (lo + hi) >> 1; if (batch[mid] < g) lo = mid + 1; else hi = mid; }
    int start = lo;
    hi = N_NODES;
    while (lo < hi) { int mid = (lo + hi) >> 1; if (batch[mid] < g + 1) lo = mid + 1; else hi = mid; }
    int end = lo;

    int c = threadIdx.x & 127;
    int half = threadIdx.x >> 7;
    float sc = scale[c], sh = shift[c];
    float s = 0.f;
    for (int r = start + half; r < end; r += 2)
        s += fmaxf(0.f, acc[r * 128 + c] * sc + sh);
    ps[threadIdx.x] = s;
    __syncthreads();
    if (half == 0)
        ps[c] = (ps[c] + ps[c + 128]) / fmaxf((float)(end - start), 1.0f);
    __syncthreads();
    if (threadIdx.x < 2) {
        int o = threadIdx.x;
        float t = 0.f;
        #pragma unroll 16
        for (int cc = 0; cc < 128; ++cc) t += ps[cc] * Wfc[cc * 2 + o];
        out[g * 2 + o] = t + bfc[o];
    }
}

// ---------------------------------------------------------------------------
extern "C" void kernel_launch(void* const* d_in, const int* in_sizes, int n_in,
                              void* d_out, int out_size, void* d_ws, size_t ws_size,
                              hipStream_t stream) {
    const float* x         = (const float*)d_in[0];
    const float* edge_attr = (const float*)d_in[1];
    const int*   eidx      = (const int*)d_in[2];
    const int*   batch     = (const int*)d_in[3];
    const float* Wn[3]  = {(const float*)d_in[4],  (const float*)d_in[8],  (const float*)d_in[12]};
    const float* bnb[3] = {(const float*)d_in[5],  (const float*)d_in[9],  (const float*)d_in[13]};
    const float* We[3]  = {(const float*)d_in[6],  (const float*)d_in[10], (const float*)d_in[14]};
    const float* be[3]  = {(const float*)d_in[7],  (const float*)d_in[11], (const float*)d_in[15]};
    const float* gm[3]  = {(const float*)d_in[16], (const float*)d_in[18], (const float*)d_in[20]};
    const float* bt[3]  = {(const float*)d_in[17], (const float*)d_in[19], (const float*)d_in[21]};
    const float* Wfc = (const float*)d_in[22];
    const float* bfc = (const float*)d_in[23];
    float* out = (float*)d_out;

    char* p = (char*)d_ws;
    auto alloc = [&](size_t bytes) {
        char* q = p;
        p += (bytes + 255) & ~size_t(255);
        return q;
    };
    float*  Ea     = (float*)alloc(sizeof(float) * N_NODES * EDGE_DIM);
    uint32* hbuf   = (uint32*)alloc(sizeof(uint32) * N_NODES * 64);   // bf16x2 packed
    float*  accA   = (float*)alloc(sizeof(float) * N_NODES * HID);
    float*  accB   = (float*)alloc(sizeof(float) * N_NODES * HID);
    float*  cs     = (float*)alloc(sizeof(float) * HID);    // cs and cq contiguous
    float*  cq     = (float*)alloc(sizeof(float) * HID);
    float*  scale  = (float*)alloc(sizeof(float) * HID);
    float*  shift  = (float*)alloc(sizeof(float) * HID);
    int*    deg    = (int*)alloc(sizeof(int) * N_NODES);
    int*    rowp   = (int*)alloc(sizeof(int) * (N_NODES + 1));
    int*    cursor = (int*)alloc(sizeof(int) * N_NODES);
    int*    csr    = (int*)alloc(sizeof(int) * N_EDGES);
    int*    csre   = (int*)alloc(sizeof(int) * N_EDGES);
    int*    bsum   = (int*)alloc(sizeof(int) * 64);
    int*    boff   = (int*)alloc(sizeof(int) * 64);

    // zero all accumulation buffers every call (harness does not re-poison)
    hipMemsetAsync(deg, 0, sizeof(int) * N_NODES, stream);
    hipMemsetAsync(cursor, 0, sizeof(int) * N_NODES, stream);

    deg_hist_kernel<<<(N_EDGES + 255) / 256, 256, 0, stream>>>(eidx, deg);
    scan_part1_kernel<<<NSCB, 256, 0, stream>>>(deg, bsum);
    scan_part2_kernel<<<1, 64, 0, stream>>>(bsum, boff);
    scan_part3_kernel<<<NSCB, 256, 0, stream>>>(deg, boff, rowp);
    fill_csr_kernel<<<(N_EDGES + 255) / 256, 256, 0, stream>>>(eidx, rowp, cursor, csr, csre);
    ea_gather_kernel<<<(N_NODES + 7) / 8, 256, 0, stream>>>(edge_attr, rowp, csre, Ea);

    float* accs[3] = {accA, accB, accA};
    const float* X = x;
    for (int l = 0; l < 3; ++l) {
        hipMemsetAsync(cs, 0, sizeof(float) * HID * 2, stream);  // cs + cq
        float* acc = accs[l];
        if (l == 0) {
            gemm_stream_kernel<false><<<256, 1024, 0, stream>>>(
                X, Wn[l], bnb[l], Ea, We[l], be[l], deg, nullptr, nullptr, hbuf, acc);
        } else {
            gemm_stream_kernel<true><<<256, 1024, 0, stream>>>(
                X, Wn[l], bnb[l], Ea, We[l], be[l], deg, scale, shift, hbuf, acc);
        }
        gather_kernel<<<(N_NODES + 3) / 4, 256, 0, stream>>>(
            hbuf, rowp, csr, acc);
        stats_kernel<<<256, 256, 0, stream>>>(acc, cs, cq);
        prep_bn_kernel<<<1, 128, 0, stream>>>(cs, cq, gm[l], bt[l], scale, shift);
        X = acc;
    }
    pool_fc_kernel<<<NUM_GRAPHS, 256, 0, stream>>>(
        accs[2], scale, shift, batch, Wfc, bfc, out);
}

// Round 7
// 462.617 us; speedup vs baseline: 2.1177x; 1.1059x over previous
//
#include <hip/hip_runtime.h>

#define N_NODES 50000
#define N_EDGES 640000
#define HID 128
#define EDGE_DIM 32
#define NUM_GRAPHS 512
#define BN_EPS 1e-5f
#define NG8 6250       // N_NODES / 8 (exact)
#define NSCB 49        // ceil(N_NODES/1024)

typedef unsigned int uint32;
typedef unsigned short ushort16;

// round-to-nearest-even f32 -> bf16 bits
__device__ inline ushort16 f2bf(float x) {
    uint32 u = __float_as_uint(x);
    return (ushort16)((u + 0x7fff + ((u >> 16) & 1)) >> 16);
}

// ---------------------------------------------------------------------------
// deg[d] = number of edges with dst == d
// ---------------------------------------------------------------------------
__global__ void deg_hist_kernel(const int* __restrict__ eidx, int* __restrict__ deg) {
    int e = blockIdx.x * 256 + threadIdx.x;
    if (e >= N_EDGES) return;
    atomicAdd(&deg[eidx[N_EDGES + e]], 1);
}

// ---------------------------------------------------------------------------
// Parallel exclusive scan of deg -> rowp, 3 dispatches
// ---------------------------------------------------------------------------
__global__ void scan_part1_kernel(const int* __restrict__ deg, int* __restrict__ bsum) {
    __shared__ int ts[256];
    int tid = threadIdx.x;
    int base = blockIdx.x * 1024 + tid * 4;
    int s = 0;
    #pragma unroll
    for (int j = 0; j < 4; ++j) { int i = base + j; if (i < N_NODES) s += deg[i]; }
    ts[tid] = s;
    __syncthreads();
    for (int off = 128; off > 0; off >>= 1) {
        if (tid < off) ts[tid] += ts[tid + off];
        __syncthreads();
    }
    if (tid == 0) bsum[blockIdx.x] = ts[0];
}

__global__ void scan_part2_kernel(const int* __restrict__ bsum, int* __restrict__ boff) {
    __shared__ int b[64];
    int t = threadIdx.x;
    b[t] = (t < NSCB) ? bsum[t] : 0;
    __syncthreads();
    if (t == 0) {
        int run = 0;
        for (int i = 0; i < NSCB; ++i) { int x = b[i]; b[i] = run; run += x; }
    }
    __syncthreads();
    if (t < NSCB) boff[t] = b[t];
}

__global__ void scan_part3_kernel(const int* __restrict__ deg, const int* __restrict__ boff,
                                  int* __restrict__ rowp) {
    __shared__ int ts[256];
    int tid = threadIdx.x;
    int base = blockIdx.x * 1024 + tid * 4;
    int v[4];
    int s = 0;
    #pragma unroll
    for (int j = 0; j < 4; ++j) {
        int i = base + j;
        v[j] = (i < N_NODES) ? deg[i] : 0;
        s += v[j];
    }
    ts[tid] = s;
    __syncthreads();
    for (int off = 1; off < 256; off <<= 1) {
        int t = (tid >= off) ? ts[tid - off] : 0;
        __syncthreads();
        ts[tid] += t;
        __syncthreads();
    }
    int excl = boff[blockIdx.x] + ts[tid] - s;
    #pragma unroll
    for (int j = 0; j < 4; ++j) {
        int i = base + j;
        if (i < N_NODES) rowp[i] = excl;
        excl += v[j];
    }
    if (blockIdx.x == 0 && tid == 0) rowp[N_NODES] = N_EDGES;
}

// CSR fill: csr_src[p] = source node, csr_eid[p] = edge id
__global__ void fill_csr_kernel(const int* __restrict__ eidx,
                                const int* __restrict__ rowp,
                                int* __restrict__ cursor,
                                int* __restrict__ csr_src,
                                int* __restrict__ csr_eid) {
    int e = blockIdx.x * 256 + threadIdx.x;
    if (e >= N_EDGES) return;
    int d = eidx[N_EDGES + e];
    int pos = rowp[d] + atomicAdd(&cursor[d], 1);
    csr_src[pos] = eidx[e];
    csr_eid[pos] = e;
}

// ---------------------------------------------------------------------------
// Ea[d] = sum of edge_attr rows with dst == d (CSR gather, no float atomics)
// half-wave (32 lanes) per node, 4-deep index prefetch + 4 independent
// accumulators for memory-level parallelism (latency-bound random rows)
// ---------------------------------------------------------------------------
__global__ __launch_bounds__(256) void ea_gather_kernel(
        const float* __restrict__ edge_attr,
        const int* __restrict__ rowp,
        const int* __restrict__ csr_eid,
        float* __restrict__ Ea) {
    int node = blockIdx.x * 8 + (threadIdx.x >> 5);
    int c = threadIdx.x & 31;
    if (node >= N_NODES) return;
    int beg = rowp[node], end = rowp[node + 1];
    float s0 = 0.f, s1 = 0.f, s2 = 0.f, s3 = 0.f;
    int p = beg;
    for (; p + 4 <= end; p += 4) {
        int e0 = csr_eid[p],     e1 = csr_eid[p + 1];
        int e2 = csr_eid[p + 2], e3 = csr_eid[p + 3];
        s0 += edge_attr[e0 * EDGE_DIM + c];
        s1 += edge_attr[e1 * EDGE_DIM + c];
        s2 += edge_attr[e2 * EDGE_DIM + c];
        s3 += edge_attr[e3 * EDGE_DIM + c];
    }
    for (; p < end; ++p)
        s0 += edge_attr[csr_eid[p] * EDGE_DIM + c];
    Ea[node * EDGE_DIM + c] = (s0 + s1) + (s2 + s3);
}

// ---------------------------------------------------------------------------
// W-resident streaming GEMM v2 (LDS-op-minimized). Per layer:
//   xin    = BN ? relu(X*scale + shift) : X
//   h[i]   = xin[i] @ Wn + bn      -> bf16 (gather operand)
//   acc[i] = h[i] + Ea[i] @ We + deg[i] * be   -> fp32
// 1024 threads = 16 waves; Wn + We resident in LDS (loaded once).
// Wave processes 8-row groups; half-wave owns 4 rows; lane owns 4 cols
// (c0 = (lane&31)*4). Inner loop per 2 k: 2x ds_read_b128 (w, 2-way
// broadcast) + 4x ds_read_b64 (X k-pairs, broadcast) -> 32 FMA.
// BN scale/shift live in registers (fixed lane->column map).
// LDS: 64K Wn + 16K We + 64K Xs = 144 KB -> 1 block/CU.
// ---------------------------------------------------------------------------
template <bool BN>
__global__ __launch_bounds__(1024) void gemm_stream_kernel(
        const float* __restrict__ X, const float* __restrict__ Wn,
        const float* __restrict__ bnb,
        const float* __restrict__ Ea, const float* __restrict__ We,
        const float* __restrict__ be, const int* __restrict__ deg,
        const float* __restrict__ scale, const float* __restrict__ shift,
        uint32* __restrict__ hb32, float* __restrict__ acc) {
    __shared__ __align__(16) float Wns[128 * 128];   // [k][c], 64 KB
    __shared__ __align__(16) float Wes[32 * 128];    // [k][c], 16 KB
    __shared__ __align__(16) float Xs[16][8][128];   // per-wave row staging, 64 KB
    int tid = threadIdx.x;

    #pragma unroll
    for (int j = 0; j < 4; ++j)
        ((float4*)Wns)[tid + j * 1024] = ((const float4*)Wn)[tid + j * 1024];
    ((float4*)Wes)[tid] = ((const float4*)We)[tid];
    __syncthreads();

    const int wid = tid >> 6, lane = tid & 63;
    const int half = lane >> 5;           // 0/1 -> rows 0-3 / 4-7
    const int c0 = (lane & 31) * 4;       // column block owned by lane

    float4 sc4, sh4;
    if (BN) { sc4 = *(const float4*)&scale[c0]; sh4 = *(const float4*)&shift[c0]; }
    const float4 bn4 = *(const float4*)&bnb[c0];
    const float4 be4 = *(const float4*)&be[c0];

    for (int g = blockIdx.x * 16 + wid; g < NG8; g += 4096) {
        const int r0 = g * 8;
        // ---- stage 4 rows x float4 (this half's rows, own columns) ----
        #pragma unroll
        for (int i = 0; i < 4; ++i) {
            int rl = half * 4 + i;
            float4 v = *(const float4*)&X[(r0 + rl) * 128 + c0];
            if (BN) {
                v.x = fmaxf(0.f, v.x * sc4.x + sh4.x);
                v.y = fmaxf(0.f, v.y * sc4.y + sh4.y);
                v.z = fmaxf(0.f, v.z * sc4.z + sh4.z);
                v.w = fmaxf(0.f, v.w * sc4.w + sh4.w);
            }
            *(float4*)&Xs[wid][rl][c0] = v;
        }
        float4 a[4];
        #pragma unroll
        for (int i = 0; i < 4; ++i) a[i] = make_float4(0.f, 0.f, 0.f, 0.f);
        // ---- node GEMM: K = 128 ----
        #pragma unroll 4
        for (int k = 0; k < 128; k += 2) {
            float4 w0 = *(const float4*)&Wns[k * 128 + c0];
            float4 w1 = *(const float4*)&Wns[(k + 1) * 128 + c0];
            #pragma unroll
            for (int i = 0; i < 4; ++i) {
                float2 xv = *(const float2*)&Xs[wid][half * 4 + i][k];
                a[i].x = fmaf(xv.x, w0.x, a[i].x); a[i].y = fmaf(xv.x, w0.y, a[i].y);
                a[i].z = fmaf(xv.x, w0.z, a[i].z); a[i].w = fmaf(xv.x, w0.w, a[i].w);
                a[i].x = fmaf(xv.y, w1.x, a[i].x); a[i].y = fmaf(xv.y, w1.y, a[i].y);
                a[i].z = fmaf(xv.y, w1.z, a[i].z); a[i].w = fmaf(xv.y, w1.w, a[i].w);
            }
        }
        // h = a + bn -> packed bf16
        #pragma unroll
        for (int i = 0; i < 4; ++i) {
            int row = r0 + half * 4 + i;
            float hx = a[i].x + bn4.x, hy = a[i].y + bn4.y;
            float hz = a[i].z + bn4.z, hw = a[i].w + bn4.w;
            uint2 pk;
            pk.x = (uint32)f2bf(hx) | ((uint32)f2bf(hy) << 16);
            pk.y = (uint32)f2bf(hz) | ((uint32)f2bf(hw) << 16);
            *(uint2*)&hb32[row * 64 + (lane & 31) * 2] = pk;
            a[i].x = hx; a[i].y = hy; a[i].z = hz; a[i].w = hw;
        }
        // ---- edge GEMM: K = 32 (stage Ea rows into Xs[wid][r][0:32]) ----
        {
            int er = lane >> 3, ec = (lane & 7) * 4;
            *(float4*)&Xs[wid][er][ec] = *(const float4*)&Ea[(r0 + er) * 32 + ec];
        }
        #pragma unroll 4
        for (int k = 0; k < 32; k += 2) {
            float4 w0 = *(const float4*)&Wes[k * 128 + c0];
            float4 w1 = *(const float4*)&Wes[(k + 1) * 128 + c0];
            #pragma unroll
            for (int i = 0; i < 4; ++i) {
                float2 xv = *(const float2*)&Xs[wid][half * 4 + i][k];
                a[i].x = fmaf(xv.x, w0.x, a[i].x); a[i].y = fmaf(xv.x, w0.y, a[i].y);
                a[i].z = fmaf(xv.x, w0.z, a[i].z); a[i].w = fmaf(xv.x, w0.w, a[i].w);
                a[i].x = fmaf(xv.y, w1.x, a[i].x); a[i].y = fmaf(xv.y, w1.y, a[i].y);
                a[i].z = fmaf(xv.y, w1.z, a[i].z); a[i].w = fmaf(xv.y, w1.w, a[i].w);
            }
        }
        #pragma unroll
        for (int i = 0; i < 4; ++i) {
            int row = r0 + half * 4 + i;
            float dg = (float)deg[row];
            float4 o;
            o.x = a[i].x + dg * be4.x; o.y = a[i].y + dg * be4.y;
            o.z = a[i].z + dg * be4.z; o.w = a[i].w + dg * be4.w;
            *(float4*)&acc[row * 128 + c0] = o;
        }
    }
}

// ---------------------------------------------------------------------------
// acc[d] += sum over CSR edges of h_bf16[src]
// one WAVE (64 lanes) per node; lane covers cols (2*lane, 2*lane+1);
// 4-deep index prefetch + 4 independent partial sums for MLP
// ---------------------------------------------------------------------------
__global__ __launch_bounds__(256) void gather_kernel(
        const uint32* __restrict__ h32,      // 64 uints (=128 bf16) per row
        const int* __restrict__ rowp, const int* __restrict__ csr_src,
        float* __restrict__ acc) {
    int node = blockIdx.x * 4 + (threadIdx.x >> 6);
    if (node >= N_NODES) return;
    int lane = threadIdx.x & 63;
    int beg = rowp[node], end = rowp[node + 1];
    float sx0 = 0.f, sy0 = 0.f, sx1 = 0.f, sy1 = 0.f;
    float sx2 = 0.f, sy2 = 0.f, sx3 = 0.f, sy3 = 0.f;
    int p = beg;
    for (; p + 4 <= end; p += 4) {
        int i0 = csr_src[p], i1 = csr_src[p + 1];
        int i2 = csr_src[p + 2], i3 = csr_src[p + 3];
        uint32 v0 = h32[i0 * 64 + lane];
        uint32 v1 = h32[i1 * 64 + lane];
        uint32 v2 = h32[i2 * 64 + lane];
        uint32 v3 = h32[i3 * 64 + lane];
        sx0 += __uint_as_float(v0 << 16); sy0 += __uint_as_float(v0 & 0xffff0000u);
        sx1 += __uint_as_float(v1 << 16); sy1 += __uint_as_float(v1 & 0xffff0000u);
        sx2 += __uint_as_float(v2 << 16); sy2 += __uint_as_float(v2 & 0xffff0000u);
        sx3 += __uint_as_float(v3 << 16); sy3 += __uint_as_float(v3 & 0xffff0000u);
    }
    for (; p < end; ++p) {
        uint32 v = h32[csr_src[p] * 64 + lane];
        sx0 += __uint_as_float(v << 16); sy0 += __uint_as_float(v & 0xffff0000u);
    }
    float2* ap = (float2*)&acc[node * 128 + lane * 2];
    float2 a = *ap;
    a.x += (sx0 + sx1) + (sx2 + sx3);
    a.y += (sy0 + sy1) + (sy2 + sy3);
    *ap = a;
}

// per-column sum / sumsq over all nodes
__global__ void stats_kernel(const float* __restrict__ acc,
                             float* __restrict__ cs, float* __restrict__ cq) {
    int c = threadIdx.x & 127;
    int rg = threadIdx.x >> 7;
    float s = 0.f, q = 0.f;
    for (int r = blockIdx.x * 2 + rg; r < N_NODES; r += gridDim.x * 2) {
        float v = acc[r * 128 + c];
        s += v; q += v * v;
    }
    unsafeAtomicAdd(&cs[c], s);
    unsafeAtomicAdd(&cq[c], q);
}

// scale/shift from column stats: y = x*scale[c] + shift[c]
__global__ void prep_bn_kernel(const float* __restrict__ cs, const float* __restrict__ cq,
                               const float* __restrict__ gamma, const float* __restrict__ beta,
                               float* __restrict__ scale, float* __restrict__ shift) {
    int c = threadIdx.x;
    const float invN = 1.0f / (float)N_NODES;
    float m = cs[c] * invN;
    float var = cq[c] * invN - m * m;
    float sc = gamma[c] * rsqrtf(var + BN_EPS);
    scale[c] = sc;
    shift[c] = beta[c] - m * sc;
}

// ---------------------------------------------------------------------------
// One block per graph (batch is sorted): binary-search node range, apply
// layer-3 BN+ReLU inline, mean-pool, then the 128->2 FC. No atomics.
// ---------------------------------------------------------------------------
__global__ __launch_bounds__(256) void pool_fc_kernel(
        const float* __restrict__ acc,
        const float* __restrict__ scale, const float* __restrict__ shift,
        const int* __restrict__ batch,
        const float* __restrict__ Wfc, const float* __restrict__ bfc,
        float* __restrict__ out) {
    __shared__ float ps[256];
    int g = blockIdx.x;
    int lo = 0, hi = N_NODES;
    while (lo < hi) { int mid = (lo + hi) >> 1; if (batch[mid] < g) lo = mid + 1; else hi = mid; }
    int start = lo;
    hi = N_NODES;
    while (lo < hi) { int mid = (lo + hi) >> 1; if (batch[mid] < g + 1) lo = mid + 1; else hi = mid; }
    int end = lo;

    int c = threadIdx.x & 127;
    int half = threadIdx.x >> 7;
    float sc = scale[c], sh = shift[c];
    float s = 0.f;
    for (int r = start + half; r < end; r += 2)
        s += fmaxf(0.f, acc[r * 128 + c] * sc + sh);
    ps[threadIdx.x] = s;
    __syncthreads();
    if (half == 0)
        ps[c] = (ps[c] + ps[c + 128]) / fmaxf((float)(end - start), 1.0f);
    __syncthreads();
    if (threadIdx.x < 2) {
        int o = threadIdx.x;
        float t = 0.f;
        #pragma unroll 16
        for (int cc = 0; cc < 128; ++cc) t += ps[cc] * Wfc[cc * 2 + o];
        out[g * 2 + o] = t + bfc[o];
    }
}

// ---------------------------------------------------------------------------
extern "C" void kernel_launch(void* const* d_in, const int* in_sizes, int n_in,
                              void* d_out, int out_size, void* d_ws, size_t ws_size,
                              hipStream_t stream) {
    const float* x         = (const float*)d_in[0];
    const float* edge_attr = (const float*)d_in[1];
    const int*   eidx      = (const int*)d_in[2];
    const int*   batch     = (const int*)d_in[3];
    const float* Wn[3]  = {(const float*)d_in[4],  (const float*)d_in[8],  (const float*)d_in[12]};
    const float* bnb[3] = {(const float*)d_in[5],  (const float*)d_in[9],  (const float*)d_in[13]};
    const float* We[3]  = {(const float*)d_in[6],  (const float*)d_in[10], (const float*)d_in[14]};
    const float* be[3]  = {(const float*)d_in[7],  (const float*)d_in[11], (const float*)d_in[15]};
    const float* gm[3]  = {(const float*)d_in[16], (const float*)d_in[18], (const float*)d_in[20]};
    const float* bt[3]  = {(const float*)d_in[17], (const float*)d_in[19], (const float*)d_in[21]};
    const float* Wfc = (const float*)d_in[22];
    const float* bfc = (const float*)d_in[23];
    float* out = (float*)d_out;

    char* p = (char*)d_ws;
    auto alloc = [&](size_t bytes) {
        char* q = p;
        p += (bytes + 255) & ~size_t(255);
        return q;
    };
    float*  Ea     = (float*)alloc(sizeof(float) * N_NODES * EDGE_DIM);
    uint32* hbuf   = (uint32*)alloc(sizeof(uint32) * N_NODES * 64);   // bf16x2 packed
    float*  accA   = (float*)alloc(sizeof(float) * N_NODES * HID);
    float*  accB   = (float*)alloc(sizeof(float) * N_NODES * HID);
    float*  cs     = (float*)alloc(sizeof(float) * HID);    // cs and cq contiguous
    float*  cq     = (float*)alloc(sizeof(float) * HID);
    float*  scale  = (float*)alloc(sizeof(float) * HID);
    float*  shift  = (float*)alloc(sizeof(float) * HID);
    int*    deg    = (int*)alloc(sizeof(int) * N_NODES);
    int*    rowp   = (int*)alloc(sizeof(int) * (N_NODES + 1));
    int*    cursor = (int*)alloc(sizeof(int) * N_NODES);
    int*    csr    = (int*)alloc(sizeof(int) * N_EDGES);
    int*    csre   = (int*)alloc(sizeof(int) * N_EDGES);
    int*    bsum   = (int*)alloc(sizeof(int) * 64);
    int*    boff   = (int*)alloc(sizeof(int) * 64);

    // zero all accumulation buffers every call (harness does not re-poison)
    hipMemsetAsync(deg, 0, sizeof(int) * N_NODES, stream);
    hipMemsetAsync(cursor, 0, sizeof(int) * N_NODES, stream);

    deg_hist_kernel<<<(N_EDGES + 255) / 256, 256, 0, stream>>>(eidx, deg);
    scan_part1_kernel<<<NSCB, 256, 0, stream>>>(deg, bsum);
    scan_part2_kernel<<<1, 64, 0, stream>>>(bsum, boff);
    scan_part3_kernel<<<NSCB, 256, 0, stream>>>(deg, boff, rowp);
    fill_csr_kernel<<<(N_EDGES + 255) / 256, 256, 0, stream>>>(eidx, rowp, cursor, csr, csre);
    ea_gather_kernel<<<(N_NODES + 7) / 8, 256, 0, stream>>>(edge_attr, rowp, csre, Ea);

    float* accs[3] = {accA, accB, accA};
    const float* X = x;
    for (int l = 0; l < 3; ++l) {
        hipMemsetAsync(cs, 0, sizeof(float) * HID * 2, stream);  // cs + cq
        float* acc = accs[l];
        if (l == 0) {
            gemm_stream_kernel<false><<<256, 1024, 0, stream>>>(
                X, Wn[l], bnb[l], Ea, We[l], be[l], deg, nullptr, nullptr, hbuf, acc);
        } else {
            gemm_stream_kernel<true><<<256, 1024, 0, stream>>>(
                X, Wn[l], bnb[l], Ea, We[l], be[l], deg, scale, shift, hbuf, acc);
        }
        gather_kernel<<<(N_NODES + 3) / 4, 256, 0, stream>>>(
            hbuf, rowp, csr, acc);
        stats_kernel<<<256, 256, 0, stream>>>(acc, cs, cq);
        prep_bn_kernel<<<1, 128, 0, stream>>>(cs, cq, gm[l], bt[l], scale, shift);
        X = acc;
    }
    pool_fc_kernel<<<NUM_GRAPHS, 256, 0, stream>>>(
        accs[2], scale, shift, batch, Wfc, bfc, out);
}